// Round 3
// baseline (164.829 us; speedup 1.0000x reference)
//
#include <hip/hip_runtime.h>

typedef unsigned short u16;
typedef __bf16 bf16x8 __attribute__((ext_vector_type(8)));
typedef float f32x4 __attribute__((ext_vector_type(4)));

#define H_HEADS 8
#define DHEAD 64
#define NSEQ 2048
#define DMODEL 512
#define BATCH 4
#define MROWS (BATCH * NSEQ)   // 8192
#define BH (BATCH * H_HEADS)   // 32

__device__ __forceinline__ u16 f2bf(float f) {
  unsigned u = __builtin_bit_cast(unsigned, f);
  u += 0x7fffu + ((u >> 16) & 1u);
  return (u16)(u >> 16);
}

__device__ __forceinline__ bf16x8 ldfrag(const u16* p) {
  return __builtin_bit_cast(bf16x8, *(const uint4*)p);
}

typedef __attribute__((address_space(1))) void GV;
typedef __attribute__((address_space(3))) void LV;
__device__ __forceinline__ void gld16(const void* g, void* l) {
  __builtin_amdgcn_global_load_lds((GV*)g, (LV*)l, 16, 0, 0);
}

// ---------------- LayerNorm: x f32 [8192][512] -> xn bf16 ----------------
__global__ __launch_bounds__(256) void ln_kernel(
    const float* __restrict__ x, const float* __restrict__ g,
    const float* __restrict__ b, u16* __restrict__ xn) {
  const int row = blockIdx.x;
  const int t = threadIdx.x;
  const float2 v = *(const float2*)(x + (size_t)row * DMODEL + t * 2);
  float s = v.x + v.y;
  float ss = v.x * v.x + v.y * v.y;
  #pragma unroll
  for (int d = 1; d < 64; d <<= 1) {
    s += __shfl_xor(s, d);
    ss += __shfl_xor(ss, d);
  }
  __shared__ float red[8];
  const int wave = t >> 6, lane = t & 63;
  if (lane == 0) { red[wave] = s; red[4 + wave] = ss; }
  __syncthreads();
  s = red[0] + red[1] + red[2] + red[3];
  ss = red[4] + red[5] + red[6] + red[7];
  const float mean = s * (1.0f / DMODEL);
  const float var = ss * (1.0f / DMODEL) - mean * mean;
  const float rstd = rsqrtf(var + 1e-5f);
  const float2 gg = *(const float2*)(g + t * 2);
  const float2 bb = *(const float2*)(b + t * 2);
  const float o0 = (v.x - mean) * rstd * gg.x + bb.x;
  const float o1 = (v.y - mean) * rstd * gg.y + bb.y;
  const unsigned packed = (unsigned)f2bf(o0) | ((unsigned)f2bf(o1) << 16);
  *(unsigned*)(xn + (size_t)row * DMODEL + t * 2) = packed;
}

// ---------------- Weight transpose (x4): W f32 [K][N] -> WT bf16 [N][K] ----------------
__global__ __launch_bounds__(256) void transpose_w4_kernel(
    const float* __restrict__ w0, const float* __restrict__ w1,
    const float* __restrict__ w2, const float* __restrict__ w3,
    u16* __restrict__ WT) {
  __shared__ float tile[32][33];
  const int z = blockIdx.z;
  const float* W = (z == 0) ? w0 : (z == 1) ? w1 : (z == 2) ? w2 : w3;
  u16* dst = WT + (size_t)z * DMODEL * DMODEL;
  const int n0 = blockIdx.x * 32, k0 = blockIdx.y * 32;
  const int t = threadIdx.x;
  #pragma unroll
  for (int p = 0; p < 4; ++p) {
    const int u = p * 256 + t;
    const int r = u >> 5, c = u & 31;
    tile[r][c] = W[(size_t)(k0 + r) * DMODEL + n0 + c];
  }
  __syncthreads();
  #pragma unroll
  for (int p = 0; p < 4; ++p) {
    const int u = p * 256 + t;
    const int rn = u >> 5, ck = u & 31;
    dst[(size_t)(n0 + rn) * DMODEL + k0 + ck] = f2bf(tile[ck][rn]);
  }
}

// ---------------- V transpose: v bf16 [BH][N][64] -> vt bf16 [BH][64][N] ----------------
#define LDK 72
__global__ __launch_bounds__(256) void transpose_v_kernel(
    const u16* __restrict__ V, u16* __restrict__ VT) {
  __shared__ u16 tile[64 * LDK];
  const int bh = blockIdx.y, n0 = blockIdx.x * 64;
  const u16* Vh = V + (size_t)bh * NSEQ * DHEAD;
  u16* Oh = VT + (size_t)bh * DHEAD * NSEQ;
  const int t = threadIdx.x;
  #pragma unroll
  for (int p = 0; p < 2; ++p) {
    const int u = p * 256 + t;
    const int r = u >> 3, ch = u & 7;
    *(uint4*)(tile + r * LDK + ch * 8) =
        *(const uint4*)(Vh + (size_t)(n0 + r) * DHEAD + ch * 8);
  }
  __syncthreads();
  #pragma unroll
  for (int p = 0; p < 2; ++p) {
    const int u = p * 256 + t;
    const int dv = u >> 3, ch = u & 7;
    union { u16 s[8]; uint4 q; } tmp;
    #pragma unroll
    for (int j = 0; j < 8; ++j) tmp.s[j] = tile[(ch * 8 + j) * LDK + dv];
    *(uint4*)(Oh + (size_t)dv * NSEQ + n0 + ch * 8) = tmp.q;
  }
}

// ---------------- GEMM 128x128, BK=64, global_load_lds, XOR-swizzled LDS ----------------
// MODE 0: fused QKV. A=xn[8192][512], BT=wqkvT[1536][512]. Writes q/k/v head layout bf16.
// MODE 1: out proj. A=attnb[8192][512], BT=woT[512][512]. Writes f32 [8192][512]+bias.
template <int MODE>
__global__ __launch_bounds__(256) void gemm128_kernel(
    const u16* __restrict__ A, const u16* __restrict__ BT,
    const float* __restrict__ bq, const float* __restrict__ bk,
    const float* __restrict__ bv,
    u16* __restrict__ qb, u16* __restrict__ kb, u16* __restrict__ vb,
    float* __restrict__ fout, int K) {
  __shared__ u16 lds_a[128 * 64];
  __shared__ u16 lds_b[128 * 64];
  const int t = threadIdx.x;
  const int lane = t & 63, wave = t >> 6;
  const int wm = wave >> 1, wn = wave & 1;
  const int lo = lane & 15, hi = lane >> 4;
  const int m0 = blockIdx.y * 128, n0 = blockIdx.x * 128;
  const int sr = lane >> 3;                       // staging row-in-chunk 0..7
  const int scol = (((lane & 7) ^ sr) * 8);       // pre-swizzled source col (elems)
  f32x4 acc[4][4] = {};
  for (int k0 = 0; k0 < K; k0 += 64) {
    #pragma unroll
    for (int j = 0; j < 4; ++j) {
      const int ch = wave * 4 + j;  // 16 chunks of 8 rows
      gld16(A + (size_t)(m0 + ch * 8 + sr) * K + k0 + scol, lds_a + ch * 512);
      gld16(BT + (size_t)(n0 + ch * 8 + sr) * K + k0 + scol, lds_b + ch * 512);
    }
    __syncthreads();
    #pragma unroll
    for (int kc = 0; kc < 2; ++kc) {
      bf16x8 af[4], bfr[4];
      const int sw = ((lo & 7) * 8);
      #pragma unroll
      for (int i = 0; i < 4; ++i)
        af[i] = ldfrag(lds_a + (wm * 64 + i * 16 + lo) * 64 + ((kc * 32 + hi * 8) ^ sw));
      #pragma unroll
      for (int i = 0; i < 4; ++i)
        bfr[i] = ldfrag(lds_b + (wn * 64 + i * 16 + lo) * 64 + ((kc * 32 + hi * 8) ^ sw));
      __builtin_amdgcn_s_setprio(1);
      #pragma unroll
      for (int mi = 0; mi < 4; ++mi)
        #pragma unroll
        for (int ni = 0; ni < 4; ++ni)
          acc[mi][ni] = __builtin_amdgcn_mfma_f32_16x16x32_bf16(
              af[mi], bfr[ni], acc[mi][ni], 0, 0, 0);
      __builtin_amdgcn_s_setprio(0);
    }
    __syncthreads();
  }
  #pragma unroll
  for (int mi = 0; mi < 4; ++mi) {
    #pragma unroll
    for (int ni = 0; ni < 4; ++ni) {
      const int col = n0 + wn * 64 + ni * 16 + lo;
      if (MODE == 0) {
        const int mat = col >> 9, w = col & 511;
        const int hh = w >> 6, dk = w & 63;
        const float bi = (mat == 0 ? bq : (mat == 1 ? bk : bv))[w];
        const float sc = (mat == 0) ? 0.125f : 1.0f;
        u16* dst = (mat == 0 ? qb : (mat == 1 ? kb : vb));
        #pragma unroll
        for (int r = 0; r < 4; ++r) {
          const int row = m0 + wm * 64 + mi * 16 + hi * 4 + r;
          const int bbx = row >> 11, seq = row & 2047;
          dst[(((size_t)(bbx * H_HEADS + hh) * NSEQ) + seq) * DHEAD + dk] =
              f2bf((acc[mi][ni][r] + bi) * sc);
        }
      } else {
        const float bi = bq[col];
        #pragma unroll
        for (int r = 0; r < 4; ++r) {
          const int row = m0 + wm * 64 + mi * 16 + hi * 4 + r;
          fout[(size_t)row * DMODEL + col] = acc[mi][ni][r] + bi;
        }
      }
    }
  }
}

// ---------------- Flash attention (causal, unpaired LPT, 4 blocks/CU) ----------------
// Q [BH][N][64] bf16 (pre-scaled), K [BH][N][64] bf16, VT [BH][64][N] bf16
// O [B][N][512] bf16.  Grid (32 qt, 32 bh); qt = 31-bx so longest blocks launch first.
__global__ __launch_bounds__(256) void attn_kernel(
    const u16* __restrict__ Q, const u16* __restrict__ K,
    const u16* __restrict__ VT, u16* __restrict__ O) {
  __shared__ u16 lds_k[2][64 * 64];
  __shared__ u16 lds_v[2][64 * 64];
  __shared__ u16 lds_p[4 * 16 * 64];   // total LDS = 40960 B -> 4 blocks/CU
  const int t = threadIdx.x;
  const int lane = t & 63, wave = t >> 6;
  const int lo = lane & 15, hi = lane >> 4;
  const int bh = blockIdx.y;
  const int b = bh >> 3, h = bh & 7;
  const u16* Qh = Q + (size_t)bh * NSEQ * DHEAD;
  const u16* Kh = K + (size_t)bh * NSEQ * DHEAD;
  const u16* Vh = VT + (size_t)bh * DHEAD * NSEQ;
  const int sr = lane >> 3;
  const int scol = (((lane & 7) ^ sr) * 8);   // pre-swizzled source col (elems)
  u16* pbase = lds_p + wave * 16 * 64;

  const int qt = 31 - (int)blockIdx.x;   // LPT: longest first
  const int q0 = qt * 64;
  const int nt = qt + 1;

  bf16x8 qf[2];
  {
    const int qr = q0 + wave * 16 + lo;
    qf[0] = ldfrag(Qh + (size_t)qr * DHEAD + hi * 8);
    qf[1] = ldfrag(Qh + (size_t)qr * DHEAD + 32 + hi * 8);
  }
  float m_r[4], l_r[4];
  f32x4 acc[4];
  #pragma unroll
  for (int r = 0; r < 4; ++r) { m_r[r] = -INFINITY; l_r[r] = 0.0f; }
  #pragma unroll
  for (int dt = 0; dt < 4; ++dt) acc[dt] = f32x4{0.f, 0.f, 0.f, 0.f};

  // prologue: stage kv-tile 0 into buf 0 (4 gld16 per thread)
  #pragma unroll
  for (int j = 0; j < 2; ++j) {
    const int ch = wave * 2 + j;  // 8 chunks of 8 rows
    gld16(Kh + (size_t)(ch * 8 + sr) * DHEAD + scol, lds_k[0] + ch * 512);
    gld16(Vh + (size_t)(ch * 8 + sr) * NSEQ + scol, lds_v[0] + ch * 512);
  }

  for (int kt = 0; kt < nt; ++kt) {
    const int cur = kt & 1;
    if (kt + 1 < nt) {
      const int kvn = (kt + 1) * 64;
      #pragma unroll
      for (int j = 0; j < 2; ++j) {
        const int ch = wave * 2 + j;
        gld16(Kh + (size_t)(kvn + ch * 8 + sr) * DHEAD + scol, lds_k[cur ^ 1] + ch * 512);
        gld16(Vh + (size_t)(ch * 8 + sr) * NSEQ + kvn + scol, lds_v[cur ^ 1] + ch * 512);
      }
      asm volatile("s_waitcnt vmcnt(4)" ::: "memory");
    } else {
      asm volatile("s_waitcnt vmcnt(0)" ::: "memory");
    }
    __builtin_amdgcn_s_barrier();
    __builtin_amdgcn_sched_barrier(0);

    const u16* lk = lds_k[cur];
    const u16* lv = lds_v[cur];
    const int sw = ((lo & 7) * 8);

    // S = Q K^T : 16 q-rows x 64 kv
    f32x4 s[4];
    #pragma unroll
    for (int tt = 0; tt < 4; ++tt) {
      f32x4 sa = {};
      __builtin_amdgcn_s_setprio(1);
      #pragma unroll
      for (int c = 0; c < 2; ++c) {
        bf16x8 kf = ldfrag(lk + (tt * 16 + lo) * 64 + ((c * 32 + hi * 8) ^ sw));
        sa = __builtin_amdgcn_mfma_f32_16x16x32_bf16(qf[c], kf, sa, 0, 0, 0);
      }
      __builtin_amdgcn_s_setprio(0);
      s[tt] = sa;
    }

    if (kt == nt - 1) {  // diagonal tile: causal mask
      #pragma unroll
      for (int tt = 0; tt < 4; ++tt) {
        const int kvc = q0 + tt * 16 + lo;
        #pragma unroll
        for (int r = 0; r < 4; ++r) {
          const int qr = q0 + wave * 16 + hi * 4 + r;
          if (kvc > qr) s[tt][r] = -1e30f;
        }
      }
    }

    // online softmax per q-row (16-lane groups)
    #pragma unroll
    for (int r = 0; r < 4; ++r) {
      float mx = fmaxf(fmaxf(s[0][r], s[1][r]), fmaxf(s[2][r], s[3][r]));
      #pragma unroll
      for (int d = 1; d < 16; d <<= 1) mx = fmaxf(mx, __shfl_xor(mx, d));
      const float mn = fmaxf(m_r[r], mx);
      const float sc = __expf(m_r[r] - mn);
      m_r[r] = mn;
      float ps = 0.0f;
      #pragma unroll
      for (int tt = 0; tt < 4; ++tt) {
        const float p = __expf(s[tt][r] - mn);
        s[tt][r] = p;
        ps += p;
      }
      #pragma unroll
      for (int d = 1; d < 16; d <<= 1) ps += __shfl_xor(ps, d);
      l_r[r] = l_r[r] * sc + ps;
      #pragma unroll
      for (int tt = 0; tt < 4; ++tt) acc[tt][r] *= sc;
    }

    // P -> per-wave LDS, swizzled stride-64 (same-wave DS ordering; no barrier)
    #pragma unroll
    for (int tt = 0; tt < 4; ++tt)
      #pragma unroll
      for (int r = 0; r < 4; ++r) {
        const int prow = hi * 4 + r;
        pbase[prow * 64 + ((tt * 16 + lo) ^ ((prow & 7) << 3))] = f2bf(s[tt][r]);
      }

    bf16x8 pf[2];
    #pragma unroll
    for (int c = 0; c < 2; ++c)
      pf[c] = ldfrag(pbase + lo * 64 + ((c * 32 + hi * 8) ^ ((lo & 7) << 3)));
    #pragma unroll
    for (int dt = 0; dt < 4; ++dt) {
      __builtin_amdgcn_s_setprio(1);
      #pragma unroll
      for (int c = 0; c < 2; ++c) {
        bf16x8 vf = ldfrag(lv + (dt * 16 + lo) * 64 + ((c * 32 + hi * 8) ^ sw));
        acc[dt] = __builtin_amdgcn_mfma_f32_16x16x32_bf16(pf[c], vf, acc[dt], 0, 0, 0);
      }
      __builtin_amdgcn_s_setprio(0);
    }
    __builtin_amdgcn_sched_barrier(0);
    __builtin_amdgcn_s_barrier();   // protect buf[cur] before next-iter overwrite
    __builtin_amdgcn_sched_barrier(0);
  }

  // epilogue: O = acc * (1/l)
  const int qrow = q0 + wave * 16 + hi * 4;
  float rl[4];
  #pragma unroll
  for (int r = 0; r < 4; ++r) rl[r] = __builtin_amdgcn_rcpf(l_r[r]);
  #pragma unroll
  for (int dt = 0; dt < 4; ++dt) {
    #pragma unroll
    for (int r = 0; r < 4; ++r) {
      const float v = acc[dt][r] * rl[r];
      O[((size_t)b * NSEQ + qrow + r) * DMODEL + h * DHEAD + dt * 16 + lo] = f2bf(v);
    }
  }
}

// ---------------- host ----------------
extern "C" void kernel_launch(void* const* d_in, const int* in_sizes, int n_in,
                              void* d_out, int out_size, void* d_ws, size_t ws_size,
                              hipStream_t stream) {
  const float* x = (const float*)d_in[0];
  // d_in[1] = attn_mask (causal, applied analytically)
  const float* ln_g = (const float*)d_in[2];
  const float* ln_b = (const float*)d_in[3];
  const float* wq = (const float*)d_in[4];
  const float* bq = (const float*)d_in[5];
  const float* wk = (const float*)d_in[6];
  const float* bk = (const float*)d_in[7];
  const float* wv = (const float*)d_in[8];
  const float* bv = (const float*)d_in[9];
  const float* wo = (const float*)d_in[10];
  const float* bo = (const float*)d_in[11];

  char* ws = (char*)d_ws;
  u16* xn = (u16*)ws;     ws += (size_t)MROWS * DMODEL * 2;
  u16* wqkvT = (u16*)ws;  ws += (size_t)4 * DMODEL * DMODEL * 2;  // q,k,v,o transposed
  u16* woT = wqkvT + (size_t)3 * DMODEL * DMODEL;
  u16* qb = (u16*)ws;     ws += (size_t)MROWS * DMODEL * 2;
  u16* kb = (u16*)ws;     ws += (size_t)MROWS * DMODEL * 2;
  u16* vb = (u16*)ws;     ws += (size_t)MROWS * DMODEL * 2;
  u16* vtb = (u16*)ws;    ws += (size_t)MROWS * DMODEL * 2;
  u16* attnb = (u16*)ws;  ws += (size_t)MROWS * DMODEL * 2;

  ln_kernel<<<MROWS, 256, 0, stream>>>(x, ln_g, ln_b, xn);
  transpose_w4_kernel<<<dim3(16, 16, 4), 256, 0, stream>>>(wq, wk, wv, wo, wqkvT);

  // fused QKV: M=8192, N=1536, K=512
  gemm128_kernel<0><<<dim3(12, 64), 256, 0, stream>>>(
      xn, wqkvT, bq, bk, bv, qb, kb, vb, nullptr, DMODEL);

  transpose_v_kernel<<<dim3(NSEQ / 64, BH), 256, 0, stream>>>(vb, vtb);

  attn_kernel<<<dim3(32, BH), 256, 0, stream>>>(qb, kb, vtb, attnb);

  // out proj: M=8192, N=512, K=512 (f32 out)
  gemm128_kernel<1><<<dim3(4, 64), 256, 0, stream>>>(
      attnb, woT, bo, nullptr, nullptr, nullptr, nullptr, nullptr,
      (float*)d_out, DMODEL);
}

// Round 4
// 139.251 us; speedup vs baseline: 1.1837x; 1.1837x over previous
//
#include <hip/hip_runtime.h>

typedef unsigned short u16;
typedef __bf16 bf16x8 __attribute__((ext_vector_type(8)));
typedef float f32x4 __attribute__((ext_vector_type(4)));

#define H_HEADS 8
#define DHEAD 64
#define NSEQ 2048
#define DMODEL 512
#define BATCH 4
#define MROWS (BATCH * NSEQ)   // 8192
#define BH (BATCH * H_HEADS)   // 32

__device__ __forceinline__ u16 f2bf(float f) {
  unsigned u = __builtin_bit_cast(unsigned, f);
  u += 0x7fffu + ((u >> 16) & 1u);
  return (u16)(u >> 16);
}

__device__ __forceinline__ bf16x8 ldfrag(const u16* p) {
  return __builtin_bit_cast(bf16x8, *(const uint4*)p);
}

typedef __attribute__((address_space(1))) void GV;
typedef __attribute__((address_space(3))) void LV;
__device__ __forceinline__ void gld16(const void* g, void* l) {
  __builtin_amdgcn_global_load_lds((GV*)g, (LV*)l, 16, 0, 0);
}

// ---------------- LayerNorm: x f32 [8192][512] -> xn bf16 ----------------
__global__ __launch_bounds__(256) void ln_kernel(
    const float* __restrict__ x, const float* __restrict__ g,
    const float* __restrict__ b, u16* __restrict__ xn) {
  const int row = blockIdx.x;
  const int t = threadIdx.x;
  const float2 v = *(const float2*)(x + (size_t)row * DMODEL + t * 2);
  float s = v.x + v.y;
  float ss = v.x * v.x + v.y * v.y;
  #pragma unroll
  for (int d = 1; d < 64; d <<= 1) {
    s += __shfl_xor(s, d);
    ss += __shfl_xor(ss, d);
  }
  __shared__ float red[8];
  const int wave = t >> 6, lane = t & 63;
  if (lane == 0) { red[wave] = s; red[4 + wave] = ss; }
  __syncthreads();
  s = red[0] + red[1] + red[2] + red[3];
  ss = red[4] + red[5] + red[6] + red[7];
  const float mean = s * (1.0f / DMODEL);
  const float var = ss * (1.0f / DMODEL) - mean * mean;
  const float rstd = rsqrtf(var + 1e-5f);
  const float2 gg = *(const float2*)(g + t * 2);
  const float2 bb = *(const float2*)(b + t * 2);
  const float o0 = (v.x - mean) * rstd * gg.x + bb.x;
  const float o1 = (v.y - mean) * rstd * gg.y + bb.y;
  const unsigned packed = (unsigned)f2bf(o0) | ((unsigned)f2bf(o1) << 16);
  *(unsigned*)(xn + (size_t)row * DMODEL + t * 2) = packed;
}

// ---------------- Weight transpose (x4): W f32 [K][N] -> WT bf16 [N][K] ----------------
__global__ __launch_bounds__(256) void transpose_w4_kernel(
    const float* __restrict__ w0, const float* __restrict__ w1,
    const float* __restrict__ w2, const float* __restrict__ w3,
    u16* __restrict__ WT) {
  __shared__ float tile[32][33];
  const int z = blockIdx.z;
  const float* W = (z == 0) ? w0 : (z == 1) ? w1 : (z == 2) ? w2 : w3;
  u16* dst = WT + (size_t)z * DMODEL * DMODEL;
  const int n0 = blockIdx.x * 32, k0 = blockIdx.y * 32;
  const int t = threadIdx.x;
  #pragma unroll
  for (int p = 0; p < 4; ++p) {
    const int u = p * 256 + t;
    const int r = u >> 5, c = u & 31;
    tile[r][c] = W[(size_t)(k0 + r) * DMODEL + n0 + c];
  }
  __syncthreads();
  #pragma unroll
  for (int p = 0; p < 4; ++p) {
    const int u = p * 256 + t;
    const int rn = u >> 5, ck = u & 31;
    dst[(size_t)(n0 + rn) * DMODEL + k0 + ck] = f2bf(tile[ck][rn]);
  }
}

// ---------------- V transpose: v bf16 [BH][N][64] -> vt bf16 [BH][64][N] ----------------
#define LDK 72
__global__ __launch_bounds__(256) void transpose_v_kernel(
    const u16* __restrict__ V, u16* __restrict__ VT) {
  __shared__ u16 tile[64 * LDK];
  const int bh = blockIdx.y, n0 = blockIdx.x * 64;
  const u16* Vh = V + (size_t)bh * NSEQ * DHEAD;
  u16* Oh = VT + (size_t)bh * DHEAD * NSEQ;
  const int t = threadIdx.x;
  #pragma unroll
  for (int p = 0; p < 2; ++p) {
    const int u = p * 256 + t;
    const int r = u >> 3, ch = u & 7;
    *(uint4*)(tile + r * LDK + ch * 8) =
        *(const uint4*)(Vh + (size_t)(n0 + r) * DHEAD + ch * 8);
  }
  __syncthreads();
  #pragma unroll
  for (int p = 0; p < 2; ++p) {
    const int u = p * 256 + t;
    const int dv = u >> 3, ch = u & 7;
    union { u16 s[8]; uint4 q; } tmp;
    #pragma unroll
    for (int j = 0; j < 8; ++j) tmp.s[j] = tile[(ch * 8 + j) * LDK + dv];
    *(uint4*)(Oh + (size_t)dv * NSEQ + n0 + ch * 8) = tmp.q;
  }
}

// ---------------- GEMM 128x128, BK=64, global_load_lds, XOR-swizzled LDS ----------------
// MODE 0: fused QKV. A=xn[8192][512], BT=wqkvT[1536][512]. Writes q/k/v head layout bf16.
//         q pre-scaled by DK^-0.5 * log2(e) so attention can use exp2.
// MODE 1: out proj. A=attnb[8192][512], BT=woT[512][512]. Writes f32 [8192][512]+bias.
template <int MODE>
__global__ __launch_bounds__(256) void gemm128_kernel(
    const u16* __restrict__ A, const u16* __restrict__ BT,
    const float* __restrict__ bq, const float* __restrict__ bk,
    const float* __restrict__ bv,
    u16* __restrict__ qb, u16* __restrict__ kb, u16* __restrict__ vb,
    float* __restrict__ fout, int K) {
  __shared__ u16 lds_a[128 * 64];
  __shared__ u16 lds_b[128 * 64];
  const int t = threadIdx.x;
  const int lane = t & 63, wave = t >> 6;
  const int wm = wave >> 1, wn = wave & 1;
  const int lo = lane & 15, hi = lane >> 4;
  const int m0 = blockIdx.y * 128, n0 = blockIdx.x * 128;
  const int sr = lane >> 3;                       // staging row-in-chunk 0..7
  const int scol = (((lane & 7) ^ sr) * 8);       // pre-swizzled source col (elems)
  f32x4 acc[4][4] = {};
  for (int k0 = 0; k0 < K; k0 += 64) {
    #pragma unroll
    for (int j = 0; j < 4; ++j) {
      const int ch = wave * 4 + j;  // 16 chunks of 8 rows
      gld16(A + (size_t)(m0 + ch * 8 + sr) * K + k0 + scol, lds_a + ch * 512);
      gld16(BT + (size_t)(n0 + ch * 8 + sr) * K + k0 + scol, lds_b + ch * 512);
    }
    __syncthreads();
    #pragma unroll
    for (int kc = 0; kc < 2; ++kc) {
      bf16x8 af[4], bfr[4];
      const int sw = ((lo & 7) * 8);
      #pragma unroll
      for (int i = 0; i < 4; ++i)
        af[i] = ldfrag(lds_a + (wm * 64 + i * 16 + lo) * 64 + ((kc * 32 + hi * 8) ^ sw));
      #pragma unroll
      for (int i = 0; i < 4; ++i)
        bfr[i] = ldfrag(lds_b + (wn * 64 + i * 16 + lo) * 64 + ((kc * 32 + hi * 8) ^ sw));
      __builtin_amdgcn_s_setprio(1);
      #pragma unroll
      for (int mi = 0; mi < 4; ++mi)
        #pragma unroll
        for (int ni = 0; ni < 4; ++ni)
          acc[mi][ni] = __builtin_amdgcn_mfma_f32_16x16x32_bf16(
              af[mi], bfr[ni], acc[mi][ni], 0, 0, 0);
      __builtin_amdgcn_s_setprio(0);
    }
    __syncthreads();
  }
  #pragma unroll
  for (int mi = 0; mi < 4; ++mi) {
    #pragma unroll
    for (int ni = 0; ni < 4; ++ni) {
      const int col = n0 + wn * 64 + ni * 16 + lo;
      if (MODE == 0) {
        const int mat = col >> 9, w = col & 511;
        const int hh = w >> 6, dk = w & 63;
        const float bi = (mat == 0 ? bq : (mat == 1 ? bk : bv))[w];
        const float sc = (mat == 0) ? 0.18033688f : 1.0f;  // 0.125*log2(e)
        u16* dst = (mat == 0 ? qb : (mat == 1 ? kb : vb));
        #pragma unroll
        for (int r = 0; r < 4; ++r) {
          const int row = m0 + wm * 64 + mi * 16 + hi * 4 + r;
          const int bbx = row >> 11, seq = row & 2047;
          dst[(((size_t)(bbx * H_HEADS + hh) * NSEQ) + seq) * DHEAD + dk] =
              f2bf((acc[mi][ni][r] + bi) * sc);
        }
      } else {
        const float bi = bq[col];
        #pragma unroll
        for (int r = 0; r < 4; ++r) {
          const int row = m0 + wm * 64 + mi * 16 + hi * 4 + r;
          fout[(size_t)row * DMODEL + col] = acc[mi][ni][r] + bi;
        }
      }
    }
  }
}

// ---------------- Flash attention (causal, balanced quads, 4 blocks/CU) ----------------
// Q [BH][N][64] bf16 (pre-scaled by 0.125*log2e), K [BH][N][64], VT [BH][64][N]
// O [B][N][512] bf16.  1024 blocks; remap so co-resident quads {n,n+256,n+512,n+768}
// have qt = {q, 31-q, q, 31-q}: every quad = 66 tile-iters.
__global__ __launch_bounds__(256) void attn_kernel(
    const u16* __restrict__ Q, const u16* __restrict__ K,
    const u16* __restrict__ VT, u16* __restrict__ O) {
  __shared__ u16 lds_k[2][64 * 64];
  __shared__ u16 lds_v[2][64 * 64];
  __shared__ u16 lds_p[4 * 16 * 64];   // total LDS = 40960 B -> 4 blocks/CU
  const int t = threadIdx.x;
  const int lane = t & 63, wave = t >> 6;
  const int lo = lane & 15, hi = lane >> 4;

  const int n = blockIdx.x;
  const int s_id = n >> 8;          // 0..3
  const int g = n & 255;
  const int q_id = g & 31;
  const int u_id = g >> 5;          // 0..7
  const int qt = (s_id & 1) ? (31 - q_id) : q_id;
  const int bh = u_id + 8 * s_id;

  const int b = bh >> 3, h = bh & 7;
  const u16* Qh = Q + (size_t)bh * NSEQ * DHEAD;
  const u16* Kh = K + (size_t)bh * NSEQ * DHEAD;
  const u16* Vh = VT + (size_t)bh * DHEAD * NSEQ;
  const int sr = lane >> 3;
  const int scol = (((lane & 7) ^ sr) * 8);   // pre-swizzled source col (elems)
  u16* pbase = lds_p + wave * 16 * 64;

  const int q0 = qt * 64;
  const int nt = qt + 1;

  bf16x8 qf[2];
  {
    const int qr = q0 + wave * 16 + lo;
    qf[0] = ldfrag(Qh + (size_t)qr * DHEAD + hi * 8);
    qf[1] = ldfrag(Qh + (size_t)qr * DHEAD + 32 + hi * 8);
  }
  float m_r[4], l_r[4];
  f32x4 acc[4];
  #pragma unroll
  for (int r = 0; r < 4; ++r) { m_r[r] = -INFINITY; l_r[r] = 0.0f; }
  #pragma unroll
  for (int dt = 0; dt < 4; ++dt) acc[dt] = f32x4{0.f, 0.f, 0.f, 0.f};

  // prologue: stage kv-tile 0 into buf 0 (4 gld16 per thread)
  #pragma unroll
  for (int j = 0; j < 2; ++j) {
    const int ch = wave * 2 + j;  // 8 chunks of 8 rows
    gld16(Kh + (size_t)(ch * 8 + sr) * DHEAD + scol, lds_k[0] + ch * 512);
    gld16(Vh + (size_t)(ch * 8 + sr) * NSEQ + scol, lds_v[0] + ch * 512);
  }

  for (int kt = 0; kt < nt; ++kt) {
    const int cur = kt & 1;
    if (kt + 1 < nt) {
      const int kvn = (kt + 1) * 64;
      #pragma unroll
      for (int j = 0; j < 2; ++j) {
        const int ch = wave * 2 + j;
        gld16(Kh + (size_t)(kvn + ch * 8 + sr) * DHEAD + scol, lds_k[cur ^ 1] + ch * 512);
        gld16(Vh + (size_t)(ch * 8 + sr) * NSEQ + kvn + scol, lds_v[cur ^ 1] + ch * 512);
      }
      asm volatile("s_waitcnt vmcnt(4)" ::: "memory");
    } else {
      asm volatile("s_waitcnt vmcnt(0)" ::: "memory");
    }
    __builtin_amdgcn_s_barrier();
    __builtin_amdgcn_sched_barrier(0);

    const u16* lk = lds_k[cur];
    const u16* lv = lds_v[cur];
    const int sw = ((lo & 7) * 8);

    // S = Q K^T : 16 q-rows x 64 kv (values pre-scaled by log2e)
    f32x4 s[4];
    #pragma unroll
    for (int tt = 0; tt < 4; ++tt) {
      f32x4 sa = {};
      __builtin_amdgcn_s_setprio(1);
      #pragma unroll
      for (int c = 0; c < 2; ++c) {
        bf16x8 kf = ldfrag(lk + (tt * 16 + lo) * 64 + ((c * 32 + hi * 8) ^ sw));
        sa = __builtin_amdgcn_mfma_f32_16x16x32_bf16(qf[c], kf, sa, 0, 0, 0);
      }
      __builtin_amdgcn_s_setprio(0);
      s[tt] = sa;
    }

    if (kt == nt - 1) {  // diagonal tile: causal mask
      #pragma unroll
      for (int tt = 0; tt < 4; ++tt) {
        const int kvc = q0 + tt * 16 + lo;
        #pragma unroll
        for (int r = 0; r < 4; ++r) {
          const int qr = q0 + wave * 16 + hi * 4 + r;
          if (kvc > qr) s[tt][r] = -1e30f;
        }
      }
    }

    // online softmax per q-row (16-lane groups), base-2 domain
    #pragma unroll
    for (int r = 0; r < 4; ++r) {
      float mx = fmaxf(fmaxf(s[0][r], s[1][r]), fmaxf(s[2][r], s[3][r]));
      #pragma unroll
      for (int d = 1; d < 16; d <<= 1) mx = fmaxf(mx, __shfl_xor(mx, d));
      const float mn = fmaxf(m_r[r], mx);
      const float sc = exp2f(m_r[r] - mn);
      m_r[r] = mn;
      float ps = 0.0f;
      #pragma unroll
      for (int tt = 0; tt < 4; ++tt) {
        const float p = exp2f(s[tt][r] - mn);
        s[tt][r] = p;
        ps += p;
      }
      #pragma unroll
      for (int d = 1; d < 16; d <<= 1) ps += __shfl_xor(ps, d);
      l_r[r] = l_r[r] * sc + ps;
      #pragma unroll
      for (int tt = 0; tt < 4; ++tt) acc[tt][r] *= sc;
    }

    // P -> per-wave LDS, swizzled stride-64 (same-wave DS ordering; no barrier)
    #pragma unroll
    for (int tt = 0; tt < 4; ++tt)
      #pragma unroll
      for (int r = 0; r < 4; ++r) {
        const int prow = hi * 4 + r;
        pbase[prow * 64 + ((tt * 16 + lo) ^ ((prow & 7) << 3))] = f2bf(s[tt][r]);
      }

    bf16x8 pf[2];
    #pragma unroll
    for (int c = 0; c < 2; ++c)
      pf[c] = ldfrag(pbase + lo * 64 + ((c * 32 + hi * 8) ^ ((lo & 7) << 3)));
    #pragma unroll
    for (int dt = 0; dt < 4; ++dt) {
      __builtin_amdgcn_s_setprio(1);
      #pragma unroll
      for (int c = 0; c < 2; ++c) {
        bf16x8 vf = ldfrag(lv + (dt * 16 + lo) * 64 + ((c * 32 + hi * 8) ^ sw));
        acc[dt] = __builtin_amdgcn_mfma_f32_16x16x32_bf16(pf[c], vf, acc[dt], 0, 0, 0);
      }
      __builtin_amdgcn_s_setprio(0);
    }
    __builtin_amdgcn_sched_barrier(0);
    __builtin_amdgcn_s_barrier();   // protect buf[cur] before next-iter overwrite
    __builtin_amdgcn_sched_barrier(0);
  }

  // epilogue: O = acc * (1/l)
  const int qrow = q0 + wave * 16 + hi * 4;
  float rl[4];
  #pragma unroll
  for (int r = 0; r < 4; ++r) rl[r] = __builtin_amdgcn_rcpf(l_r[r]);
  #pragma unroll
  for (int dt = 0; dt < 4; ++dt) {
    #pragma unroll
    for (int r = 0; r < 4; ++r) {
      const float v = acc[dt][r] * rl[r];
      O[((size_t)b * NSEQ + qrow + r) * DMODEL + h * DHEAD + dt * 16 + lo] = f2bf(v);
    }
  }
}

// ---------------- host ----------------
extern "C" void kernel_launch(void* const* d_in, const int* in_sizes, int n_in,
                              void* d_out, int out_size, void* d_ws, size_t ws_size,
                              hipStream_t stream) {
  const float* x = (const float*)d_in[0];
  // d_in[1] = attn_mask (causal, applied analytically)
  const float* ln_g = (const float*)d_in[2];
  const float* ln_b = (const float*)d_in[3];
  const float* wq = (const float*)d_in[4];
  const float* bq = (const float*)d_in[5];
  const float* wk = (const float*)d_in[6];
  const float* bk = (const float*)d_in[7];
  const float* wv = (const float*)d_in[8];
  const float* bv = (const float*)d_in[9];
  const float* wo = (const float*)d_in[10];
  const float* bo = (const float*)d_in[11];

  char* ws = (char*)d_ws;
  u16* xn = (u16*)ws;     ws += (size_t)MROWS * DMODEL * 2;
  u16* wqkvT = (u16*)ws;  ws += (size_t)4 * DMODEL * DMODEL * 2;  // q,k,v,o transposed
  u16* woT = wqkvT + (size_t)3 * DMODEL * DMODEL;
  u16* qb = (u16*)ws;     ws += (size_t)MROWS * DMODEL * 2;
  u16* kb = (u16*)ws;     ws += (size_t)MROWS * DMODEL * 2;
  u16* vb = (u16*)ws;     ws += (size_t)MROWS * DMODEL * 2;
  u16* vtb = (u16*)ws;    ws += (size_t)MROWS * DMODEL * 2;
  u16* attnb = (u16*)ws;  ws += (size_t)MROWS * DMODEL * 2;

  ln_kernel<<<MROWS, 256, 0, stream>>>(x, ln_g, ln_b, xn);
  transpose_w4_kernel<<<dim3(16, 16, 4), 256, 0, stream>>>(wq, wk, wv, wo, wqkvT);

  // fused QKV: M=8192, N=1536, K=512
  gemm128_kernel<0><<<dim3(12, 64), 256, 0, stream>>>(
      xn, wqkvT, bq, bk, bv, qb, kb, vb, nullptr, DMODEL);

  transpose_v_kernel<<<dim3(NSEQ / 64, BH), 256, 0, stream>>>(vb, vtb);

  attn_kernel<<<1024, 256, 0, stream>>>(qb, kb, vtb, attnb);

  // out proj: M=8192, N=512, K=512 (f32 out)
  gemm128_kernel<1><<<dim3(4, 64), 256, 0, stream>>>(
      attnb, woT, bo, nullptr, nullptr, nullptr, nullptr, nullptr,
      (float*)d_out, DMODEL);
}

// Round 6
// 111.624 us; speedup vs baseline: 1.4766x; 1.2475x over previous
//
#include <hip/hip_runtime.h>

typedef unsigned short u16;
typedef unsigned long long u64;
typedef __bf16 bf16x8 __attribute__((ext_vector_type(8)));
typedef float f32x4 __attribute__((ext_vector_type(4)));
typedef float f32x16 __attribute__((ext_vector_type(16)));

#define H_HEADS 8
#define DHEAD 64
#define NSEQ 2048
#define DMODEL 512
#define BATCH 4
#define MROWS (BATCH * NSEQ)   // 8192
#define BH (BATCH * H_HEADS)   // 32

__device__ __forceinline__ u16 f2bf(float f) {
  unsigned u = __builtin_bit_cast(unsigned, f);
  u += 0x7fffu + ((u >> 16) & 1u);
  return (u16)(u >> 16);
}

__device__ __forceinline__ bf16x8 ldfrag(const u16* p) {
  return __builtin_bit_cast(bf16x8, *(const uint4*)p);
}

typedef __attribute__((address_space(1))) void GV;
typedef __attribute__((address_space(3))) void LV;
__device__ __forceinline__ void gld16(const void* g, void* l) {
  __builtin_amdgcn_global_load_lds((GV*)g, (LV*)l, 16, 0, 0);
}

// ---------------- LayerNorm: x f32 [8192][512] -> xn bf16 ----------------
__global__ __launch_bounds__(256) void ln_kernel(
    const float* __restrict__ x, const float* __restrict__ g,
    const float* __restrict__ b, u16* __restrict__ xn) {
  const int row = blockIdx.x;
  const int t = threadIdx.x;
  const float2 v = *(const float2*)(x + (size_t)row * DMODEL + t * 2);
  float s = v.x + v.y;
  float ss = v.x * v.x + v.y * v.y;
  #pragma unroll
  for (int d = 1; d < 64; d <<= 1) {
    s += __shfl_xor(s, d);
    ss += __shfl_xor(ss, d);
  }
  __shared__ float red[8];
  const int wave = t >> 6, lane = t & 63;
  if (lane == 0) { red[wave] = s; red[4 + wave] = ss; }
  __syncthreads();
  s = red[0] + red[1] + red[2] + red[3];
  ss = red[4] + red[5] + red[6] + red[7];
  const float mean = s * (1.0f / DMODEL);
  const float var = ss * (1.0f / DMODEL) - mean * mean;
  const float rstd = rsqrtf(var + 1e-5f);
  const float2 gg = *(const float2*)(g + t * 2);
  const float2 bb = *(const float2*)(b + t * 2);
  const float o0 = (v.x - mean) * rstd * gg.x + bb.x;
  const float o1 = (v.y - mean) * rstd * gg.y + bb.y;
  const unsigned packed = (unsigned)f2bf(o0) | ((unsigned)f2bf(o1) << 16);
  *(unsigned*)(xn + (size_t)row * DMODEL + t * 2) = packed;
}

// ---------------- Weight transpose (x4): W f32 [K][N] -> WT bf16 [N][K] ----------------
__global__ __launch_bounds__(256) void transpose_w4_kernel(
    const float* __restrict__ w0, const float* __restrict__ w1,
    const float* __restrict__ w2, const float* __restrict__ w3,
    u16* __restrict__ WT) {
  __shared__ float tile[32][33];
  const int z = blockIdx.z;
  const float* W = (z == 0) ? w0 : (z == 1) ? w1 : (z == 2) ? w2 : w3;
  u16* dst = WT + (size_t)z * DMODEL * DMODEL;
  const int n0 = blockIdx.x * 32, k0 = blockIdx.y * 32;
  const int t = threadIdx.x;
  #pragma unroll
  for (int p = 0; p < 4; ++p) {
    const int u = p * 256 + t;
    const int r = u >> 5, c = u & 31;
    tile[r][c] = W[(size_t)(k0 + r) * DMODEL + n0 + c];
  }
  __syncthreads();
  #pragma unroll
  for (int p = 0; p < 4; ++p) {
    const int u = p * 256 + t;
    const int rn = u >> 5, ck = u & 31;
    dst[(size_t)(n0 + rn) * DMODEL + k0 + ck] = f2bf(tile[ck][rn]);
  }
}

// ---------------- GEMM 128x128, BK=64, global_load_lds, XOR-swizzled LDS ----------------
// MODE 0: fused QKV. A=xn[8192][512], BT=wqkvT[1536][512].
//         q (scaled by 0.125*log2e) and k -> head layout [BH][N][64] bf16;
//         v -> TRANSPOSED head layout vtb [BH][64][N] bf16 (packed 4-row stores).
// MODE 1: out proj. A=attnb[8192][512], BT=woT[512][512]. Writes f32 [8192][512]+bias.
template <int MODE>
__global__ __launch_bounds__(256) void gemm128_kernel(
    const u16* __restrict__ A, const u16* __restrict__ BT,
    const float* __restrict__ bq, const float* __restrict__ bk,
    const float* __restrict__ bv,
    u16* __restrict__ qb, u16* __restrict__ kb, u16* __restrict__ vtb,
    float* __restrict__ fout, int K) {
  __shared__ u16 lds_a[128 * 64];
  __shared__ u16 lds_b[128 * 64];
  const int t = threadIdx.x;
  const int lane = t & 63, wave = t >> 6;
  const int wm = wave >> 1, wn = wave & 1;
  const int lo = lane & 15, hi = lane >> 4;
  const int m0 = blockIdx.y * 128, n0 = blockIdx.x * 128;
  const int sr = lane >> 3;                       // staging row-in-chunk 0..7
  const int scol = (((lane & 7) ^ sr) * 8);       // pre-swizzled source col (elems)
  f32x4 acc[4][4] = {};
  for (int k0 = 0; k0 < K; k0 += 64) {
    #pragma unroll
    for (int j = 0; j < 4; ++j) {
      const int ch = wave * 4 + j;  // 16 chunks of 8 rows
      gld16(A + (size_t)(m0 + ch * 8 + sr) * K + k0 + scol, lds_a + ch * 512);
      gld16(BT + (size_t)(n0 + ch * 8 + sr) * K + k0 + scol, lds_b + ch * 512);
    }
    __syncthreads();
    #pragma unroll
    for (int kc = 0; kc < 2; ++kc) {
      bf16x8 af[4], bfr[4];
      const int sw = ((lo & 7) * 8);
      #pragma unroll
      for (int i = 0; i < 4; ++i)
        af[i] = ldfrag(lds_a + (wm * 64 + i * 16 + lo) * 64 + ((kc * 32 + hi * 8) ^ sw));
      #pragma unroll
      for (int i = 0; i < 4; ++i)
        bfr[i] = ldfrag(lds_b + (wn * 64 + i * 16 + lo) * 64 + ((kc * 32 + hi * 8) ^ sw));
      __builtin_amdgcn_s_setprio(1);
      #pragma unroll
      for (int mi = 0; mi < 4; ++mi)
        #pragma unroll
        for (int ni = 0; ni < 4; ++ni)
          acc[mi][ni] = __builtin_amdgcn_mfma_f32_16x16x32_bf16(
              af[mi], bfr[ni], acc[mi][ni], 0, 0, 0);
      __builtin_amdgcn_s_setprio(0);
    }
    __syncthreads();
  }
  #pragma unroll
  for (int mi = 0; mi < 4; ++mi) {
    #pragma unroll
    for (int ni = 0; ni < 4; ++ni) {
      const int col = n0 + wn * 64 + ni * 16 + lo;
      if (MODE == 0) {
        const int mat = col >> 9, w = col & 511;
        const int hh = w >> 6, dk = w & 63;
        const float bi = (mat == 0 ? bq : (mat == 1 ? bk : bv))[w];
        const int row0 = m0 + wm * 64 + mi * 16 + hi * 4;
        const int bbx = row0 >> 11, seq0 = row0 & 2047;
        if (mat == 2) {
          // transposed V write: vtb[(bh*64 + dk)*2048 + seq], 4 consecutive seq
          u64 pk = 0;
          #pragma unroll
          for (int r = 0; r < 4; ++r)
            pk |= (u64)f2bf(acc[mi][ni][r] + bi) << (16 * r);
          *(u64*)(vtb + ((size_t)(bbx * H_HEADS + hh) * DHEAD + dk) * NSEQ + seq0) = pk;
        } else {
          const float sc = (mat == 0) ? 0.18033688f : 1.0f;  // 0.125*log2(e)
          u16* dst = (mat == 0 ? qb : kb);
          #pragma unroll
          for (int r = 0; r < 4; ++r)
            dst[(((size_t)(bbx * H_HEADS + hh) * NSEQ) + seq0 + r) * DHEAD + dk] =
                f2bf((acc[mi][ni][r] + bi) * sc);
        }
      } else {
        const float bi = bq[col];
        #pragma unroll
        for (int r = 0; r < 4; ++r) {
          const int row = m0 + wm * 64 + mi * 16 + hi * 4 + r;
          fout[(size_t)row * DMODEL + col] = acc[mi][ni][r] + bi;
        }
      }
    }
  }
}

// ---------------- Flash attention: 32x32 swapped-operand, lane-local softmax ----------
// Q [BH][N][64] bf16 (pre-scaled by 0.125*log2e), K [BH][N][64], VT [BH][64][N]
// O [B][N][512] bf16.
// Block = 4 warps x 32 q-rows (QBLK=128). 512 blocks; co-resident pair {i, 15-i}.
// Per kv-tile: S^T = mfma(K,Q) (lane owns one q-row), in-lane softmax,
// P->bf16 via v_cvt_pk + v_permlane32_swap, O^T = mfma(V^T, P).
__global__ __launch_bounds__(256, 2) void attn_kernel(
    const u16* __restrict__ Q, const u16* __restrict__ K,
    const u16* __restrict__ VT, u16* __restrict__ O) {
  __shared__ u16 lds_k[2][4096];
  __shared__ u16 lds_v[2][4096];
  const int t = threadIdx.x;
  const int lane = t & 63, wave = t >> 6;
  const int l31 = lane & 31, hi = lane >> 5;
  const int l7 = lane & 7;

  const int n = blockIdx.x;
  const int s_id = n >> 8, g = n & 255;
  const int u_id = g >> 4, q_id = g & 15;
  const int ist = (s_id & 1) ? (15 - q_id) : q_id;   // co-resident {i, 15-i}
  const int bh = u_id + 16 * s_id;
  const int b = bh >> 3, h = bh & 7;

  const u16* Qh = Q + (size_t)bh * NSEQ * DHEAD;
  const u16* Kh = K + (size_t)bh * NSEQ * DHEAD;
  const u16* Vh = VT + (size_t)bh * DHEAD * NSEQ;

  const int q0w = ist * 128 + wave * 32;
  const int nt = 2 * ist + 2;
  const int lastkt = (q0w + 31) >> 6;   // warp's diagonal tile; beyond = fully masked
  const int qrow = q0w + l31;

  bf16x8 qf[4];
  #pragma unroll
  for (int c = 0; c < 4; ++c)
    qf[c] = ldfrag(Qh + (size_t)qrow * DHEAD + c * 16 + hi * 8);

  f32x16 o0 = {}, o1 = {};
  float m = -INFINITY, l = 0.0f;

  const int sr = lane >> 3;
  const int scol = ((lane & 7) ^ sr) * 8;  // pre-swizzled global source col
  const int swz = l7 * 8;                  // read-side XOR

  #pragma unroll
  for (int j = 0; j < 2; ++j) {
    const int ch = wave * 2 + j;
    gld16(Kh + (size_t)(ch * 8 + sr) * DHEAD + scol, lds_k[0] + ch * 512);
    gld16(Vh + (size_t)(ch * 8 + sr) * NSEQ + scol, lds_v[0] + ch * 512);
  }

  for (int kt = 0; kt < nt; ++kt) {
    const int cur = kt & 1;
    if (kt + 1 < nt) {
      const int kvn = (kt + 1) * 64;
      #pragma unroll
      for (int j = 0; j < 2; ++j) {
        const int ch = wave * 2 + j;
        gld16(Kh + (size_t)(kvn + ch * 8 + sr) * DHEAD + scol, lds_k[cur ^ 1] + ch * 512);
        gld16(Vh + (size_t)(ch * 8 + sr) * NSEQ + kvn + scol, lds_v[cur ^ 1] + ch * 512);
      }
      asm volatile("s_waitcnt vmcnt(4)" ::: "memory");
    } else {
      asm volatile("s_waitcnt vmcnt(0)" ::: "memory");
    }
    __builtin_amdgcn_s_barrier();
    __builtin_amdgcn_sched_barrier(0);

    if (kt <= lastkt) {
      const u16* lk = lds_k[cur];
      const u16* lv = lds_v[cur];
      f32x16 st0 = {}, st1 = {};

      // S^T = mfma(K, Q): lane -> q-col = l31, 16 kv rows per sub
      __builtin_amdgcn_s_setprio(1);
      #pragma unroll
      for (int c = 0; c < 4; ++c) {
        const int col = (c * 16 + hi * 8) ^ swz;
        bf16x8 kf0 = ldfrag(lk + l31 * 64 + col);
        bf16x8 kf1 = ldfrag(lk + (32 + l31) * 64 + col);
        st0 = __builtin_amdgcn_mfma_f32_32x32x16_bf16(kf0, qf[c], st0, 0, 0, 0);
        st1 = __builtin_amdgcn_mfma_f32_32x32x16_bf16(kf1, qf[c], st1, 0, 0, 0);
      }
      __builtin_amdgcn_s_setprio(0);

      if (kt == lastkt) {  // causal mask, lane-local
        const int kvb = kt * 64 + 4 * hi;
        #pragma unroll
        for (int r = 0; r < 16; ++r) {
          const int kv = kvb + (r & 3) + 8 * (r >> 2);
          if (kv > qrow) st0[r] = -1e30f;
          if (kv + 32 > qrow) st1[r] = -1e30f;
        }
      }

      // in-lane softmax (one q-row per lane; partner lane 32 holds other half)
      float pm = st0[0];
      #pragma unroll
      for (int r = 1; r < 16; ++r) pm = fmaxf(pm, st0[r]);
      #pragma unroll
      for (int r = 0; r < 16; ++r) pm = fmaxf(pm, st1[r]);
      pm = fmaxf(pm, __shfl_xor(pm, 32));
      const float mn = fmaxf(m, pm);
      const float sc = exp2f(m - mn);
      m = mn;
      float ps = 0.0f;
      #pragma unroll
      for (int r = 0; r < 16; ++r) { st0[r] = exp2f(st0[r] - mn); ps += st0[r]; }
      #pragma unroll
      for (int r = 0; r < 16; ++r) { st1[r] = exp2f(st1[r] - mn); ps += st1[r]; }
      ps += __shfl_xor(ps, 32);
      l = l * sc + ps;
      #pragma unroll
      for (int r = 0; r < 16; ++r) { o0[r] *= sc; o1[r] *= sc; }

      // P -> bf16 B-frags in-register: cvt_pk pairs + permlane32 half-swap
      bf16x8 pf0, pf1, pf2, pf3;
      {
        unsigned w0, w1, w2, w3, w4, w5, w6, w7;
        asm("v_cvt_pk_bf16_f32 %0, %1, %2" : "=v"(w0) : "v"(st0[0]), "v"(st0[1]));
        asm("v_cvt_pk_bf16_f32 %0, %1, %2" : "=v"(w1) : "v"(st0[2]), "v"(st0[3]));
        asm("v_cvt_pk_bf16_f32 %0, %1, %2" : "=v"(w2) : "v"(st0[4]), "v"(st0[5]));
        asm("v_cvt_pk_bf16_f32 %0, %1, %2" : "=v"(w3) : "v"(st0[6]), "v"(st0[7]));
        asm("v_cvt_pk_bf16_f32 %0, %1, %2" : "=v"(w4) : "v"(st0[8]), "v"(st0[9]));
        asm("v_cvt_pk_bf16_f32 %0, %1, %2" : "=v"(w5) : "v"(st0[10]), "v"(st0[11]));
        asm("v_cvt_pk_bf16_f32 %0, %1, %2" : "=v"(w6) : "v"(st0[12]), "v"(st0[13]));
        asm("v_cvt_pk_bf16_f32 %0, %1, %2" : "=v"(w7) : "v"(st0[14]), "v"(st0[15]));
        asm("v_permlane32_swap_b32 %0, %1" : "+v"(w0), "+v"(w2));
        asm("v_permlane32_swap_b32 %0, %1" : "+v"(w1), "+v"(w3));
        asm("v_permlane32_swap_b32 %0, %1" : "+v"(w4), "+v"(w6));
        asm("v_permlane32_swap_b32 %0, %1" : "+v"(w5), "+v"(w7));
        union Uu { unsigned u[4]; bf16x8 v; };
        Uu a; a.u[0] = w0; a.u[1] = w1; a.u[2] = w2; a.u[3] = w3; pf0 = a.v;
        Uu bb; bb.u[0] = w4; bb.u[1] = w5; bb.u[2] = w6; bb.u[3] = w7; pf1 = bb.v;
      }
      {
        unsigned w0, w1, w2, w3, w4, w5, w6, w7;
        asm("v_cvt_pk_bf16_f32 %0, %1, %2" : "=v"(w0) : "v"(st1[0]), "v"(st1[1]));
        asm("v_cvt_pk_bf16_f32 %0, %1, %2" : "=v"(w1) : "v"(st1[2]), "v"(st1[3]));
        asm("v_cvt_pk_bf16_f32 %0, %1, %2" : "=v"(w2) : "v"(st1[4]), "v"(st1[5]));
        asm("v_cvt_pk_bf16_f32 %0, %1, %2" : "=v"(w3) : "v"(st1[6]), "v"(st1[7]));
        asm("v_cvt_pk_bf16_f32 %0, %1, %2" : "=v"(w4) : "v"(st1[8]), "v"(st1[9]));
        asm("v_cvt_pk_bf16_f32 %0, %1, %2" : "=v"(w5) : "v"(st1[10]), "v"(st1[11]));
        asm("v_cvt_pk_bf16_f32 %0, %1, %2" : "=v"(w6) : "v"(st1[12]), "v"(st1[13]));
        asm("v_cvt_pk_bf16_f32 %0, %1, %2" : "=v"(w7) : "v"(st1[14]), "v"(st1[15]));
        asm("v_permlane32_swap_b32 %0, %1" : "+v"(w0), "+v"(w2));
        asm("v_permlane32_swap_b32 %0, %1" : "+v"(w1), "+v"(w3));
        asm("v_permlane32_swap_b32 %0, %1" : "+v"(w4), "+v"(w6));
        asm("v_permlane32_swap_b32 %0, %1" : "+v"(w5), "+v"(w7));
        union Uu { unsigned u[4]; bf16x8 v; };
        Uu a; a.u[0] = w0; a.u[1] = w1; a.u[2] = w2; a.u[3] = w3; pf2 = a.v;
        Uu bb; bb.u[0] = w4; bb.u[1] = w5; bb.u[2] = w6; bb.u[3] = w7; pf3 = bb.v;
      }

      // O^T += V^T . P^T : lane -> q-col = l31 (same as softmax layout)
      __builtin_amdgcn_s_setprio(1);
      #pragma unroll
      for (int c = 0; c < 4; ++c) {
        const int col = (c * 16 + hi * 8) ^ swz;
        bf16x8 vf0 = ldfrag(lv + l31 * 64 + col);
        bf16x8 vf1 = ldfrag(lv + (32 + l31) * 64 + col);
        const bf16x8 pc = (c == 0) ? pf0 : (c == 1) ? pf1 : (c == 2) ? pf2 : pf3;
        o0 = __builtin_amdgcn_mfma_f32_32x32x16_bf16(vf0, pc, o0, 0, 0, 0);
        o1 = __builtin_amdgcn_mfma_f32_32x32x16_bf16(vf1, pc, o1, 0, 0, 0);
      }
      __builtin_amdgcn_s_setprio(0);
    }
    __builtin_amdgcn_sched_barrier(0);
    __builtin_amdgcn_s_barrier();   // protect buf[cur] before next-iter prefetch
    __builtin_amdgcn_sched_barrier(0);
  }

  // epilogue: O[b][qrow][h*64 + dv] = o^T * (1/l); dv = 32d + 8mq + 4hi + c3
  const float rl = __builtin_amdgcn_rcpf(l);
  u16* Ob = O + ((size_t)b * NSEQ + qrow) * DMODEL + h * DHEAD;
  #pragma unroll
  for (int d = 0; d < 2; ++d) {
    #pragma unroll
    for (int mq = 0; mq < 4; ++mq) {
      u64 pk = 0;
      #pragma unroll
      for (int c3 = 0; c3 < 4; ++c3) {
        const float v = (d ? o1[mq * 4 + c3] : o0[mq * 4 + c3]) * rl;
        pk |= (u64)f2bf(v) << (16 * c3);
      }
      *(u64*)(Ob + d * 32 + mq * 8 + hi * 4) = pk;
    }
  }
}

// ---------------- host ----------------
extern "C" void kernel_launch(void* const* d_in, const int* in_sizes, int n_in,
                              void* d_out, int out_size, void* d_ws, size_t ws_size,
                              hipStream_t stream) {
  const float* x = (const float*)d_in[0];
  // d_in[1] = attn_mask (causal, applied analytically)
  const float* ln_g = (const float*)d_in[2];
  const float* ln_b = (const float*)d_in[3];
  const float* wq = (const float*)d_in[4];
  const float* bq = (const float*)d_in[5];
  const float* wk = (const float*)d_in[6];
  const float* bk = (const float*)d_in[7];
  const float* wv = (const float*)d_in[8];
  const float* bv = (const float*)d_in[9];
  const float* wo = (const float*)d_in[10];
  const float* bo = (const float*)d_in[11];

  char* ws = (char*)d_ws;
  u16* xn = (u16*)ws;     ws += (size_t)MROWS * DMODEL * 2;
  u16* wqkvT = (u16*)ws;  ws += (size_t)4 * DMODEL * DMODEL * 2;  // q,k,v,o transposed
  u16* woT = wqkvT + (size_t)3 * DMODEL * DMODEL;
  u16* qb = (u16*)ws;     ws += (size_t)MROWS * DMODEL * 2;
  u16* kb = (u16*)ws;     ws += (size_t)MROWS * DMODEL * 2;
  u16* vtb = (u16*)ws;    ws += (size_t)MROWS * DMODEL * 2;
  u16* attnb = (u16*)ws;  ws += (size_t)MROWS * DMODEL * 2;

  ln_kernel<<<MROWS, 256, 0, stream>>>(x, ln_g, ln_b, xn);
  transpose_w4_kernel<<<dim3(16, 16, 4), 256, 0, stream>>>(wq, wk, wv, wo, wqkvT);

  // fused QKV: M=8192, N=1536, K=512 (v written transposed)
  gemm128_kernel<0><<<dim3(12, 64), 256, 0, stream>>>(
      xn, wqkvT, bq, bk, bv, qb, kb, vtb, nullptr, DMODEL);

  attn_kernel<<<512, 256, 0, stream>>>(qb, kb, vtb, attnb);

  // out proj: M=8192, N=512, K=512 (f32 out)
  gemm128_kernel<1><<<dim3(4, 64), 256, 0, stream>>>(
      attnb, woT, bo, nullptr, nullptr, nullptr, nullptr, nullptr,
      (float*)d_out, DMODEL);
}